// Round 4
// baseline (68.560 us; speedup 1.0000x reference)
//
#include <hip/hip_runtime.h>

// ConditionalSplineSQ2D: B=32, M=16, K=32, Kc=31.
// Z = X^T D Y per (bm,i,j): X,Y are the 10 pair-products of cx/cy,
// D is the 136 triu coeffs folded to 10x10 per (i,j) by a prepass.
// Outputs: poly [32,16,2,31,4] = 126976 floats, then Z [32,16,31,31].

#define BM_TOTAL 512
#define KC 31
#define NPAIR 136
#define POLY_ITEMS 31744   // BM_TOTAL * 2 * KC (one float4 each)
#define POLY_FLOATS 126976
#define Z_STRIDE 961       // KC*KC
#define D_STRIDE 128       // padded D block per (i,j) in ws, floats

// ---------------- prepass: fold C[136] -> D[10][10] per (i,j) -------------
__global__ __launch_bounds__(128) void spline_prepass(
    const float* __restrict__ coeffs,  // [31,31,136]
    float* __restrict__ ws)            // [961 * D_STRIDE]
{
    const int t = threadIdx.x;
    const int blk = blockIdx.x;
    if (t >= 100) return;
    const int al = t / 10, be = t % 10;
    // q -> (a, a2), a<=a2, row-major pair order (matches X/Y build below)
    const int TA [10] = {0,0,0,0,1,1,1,2,2,3};
    const int TA2[10] = {0,1,2,3,1,2,3,2,3,3};
    const int a = TA[al], a2 = TA2[al];
    const int c = TA[be], c2 = TA2[be];
    const float* C = coeffs + blk * NPAIR;
    // np.triu_indices(16) row-major flat index of pair (u,v), u<=v
    auto pidx = [](int u, int v) { return u * 16 - (u * (u - 1)) / 2 + (v - u); };
    float val;
    if (a == a2) {
        // only u<=v pairs exist: c<=c2 (guaranteed by table order)
        val = C[pidx(4 * a + c, 4 * a + c2)];
    } else {
        // a<a2: u=4a+* < v=4a2+* always
        val = C[pidx(4 * a + c, 4 * a2 + c2)];
        if (c != c2) val += C[pidx(4 * a + c2, 4 * a2 + c)];
    }
    ws[blk * D_STRIDE + t] = val;
}

// ---------------- main: poly + Z ------------------------------------------
__global__ __launch_bounds__(256) void spline_main(
    const float* __restrict__ params,   // [512, 2, 32, 2]
    const float* __restrict__ knots,    // [32, 2]
    const float* __restrict__ ws,       // [961 * D_STRIDE] (D matrices)
    float* __restrict__ out)            // [126976 + 492032]
{
    const int tid = threadIdx.x;
    const int blk = blockIdx.x;

    // Fused side-task: poly output (unchanged from passing version).
    if (blk < (POLY_ITEMS / 256)) {
        const int gid = blk * 256 + tid;          // 0..31743
        const int k   = gid % KC;
        const int rem = gid / KC;                 // bm*2 + dim
        const int dim = rem & 1;
        const float* p = params + (rem * 32 + k) * 2;
        const float2 v0 = *(const float2*)(p);
        const float2 v1 = *(const float2*)(p + 2);
        const float y0 = v0.x, d0 = v0.y, y1 = v1.x, d1 = v1.y;
        const float h  = knots[(k + 1) * 2 + dim] - knots[k * 2 + dim];
        const float c2 = 3.0f * (y1 - y0) / (h * h) - (2.0f * d0 + d1) / h;
        const float c3 = 2.0f * (y0 - y1) / (h * h * h) + (d0 + d1) / (h * h);
        float4 o; o.x = y0; o.y = d0; o.z = c2; o.w = c3;
        ((float4*)out)[gid] = o;
    }

    const int i = blk / KC;
    const int j = blk % KC;

    const float hx = knots[(i + 1) * 2 + 0] - knots[i * 2 + 0];
    const float hy = knots[(j + 1) * 2 + 1] - knots[j * 2 + 1];
    const float ihx = 1.0f / hx, ihx2 = ihx * ihx, ihx3 = ihx2 * ihx;
    const float ihy = 1.0f / hy, ihy2 = ihy * ihy, ihy3 = ihy2 * ihy;

    // Two bm slots per thread: bm0 = tid, bm1 = tid + 256.
    const int bm0 = tid, bm1 = tid + 256;
    const float* px0 = params + (bm0 * 64 + i) * 2;        // dim 0
    const float2 a00 = *(const float2*)px0;
    const float2 a01 = *(const float2*)(px0 + 2);
    const float* py0 = params + (bm0 * 64 + 32 + j) * 2;   // dim 1
    const float2 b00 = *(const float2*)py0;
    const float2 b01 = *(const float2*)(py0 + 2);
    const float* px1 = params + (bm1 * 64 + i) * 2;
    const float2 a10 = *(const float2*)px1;
    const float2 a11 = *(const float2*)(px1 + 2);
    const float* py1 = params + (bm1 * 64 + 32 + j) * 2;
    const float2 b10 = *(const float2*)py1;
    const float2 b11 = *(const float2*)(py1 + 2);

    float cx0[4], cy0[4], cx1[4], cy1[4];
    cx0[0] = a00.x; cx0[1] = a00.y;
    cx0[2] = 3.0f * (a01.x - a00.x) * ihx2 - (2.0f * a00.y + a01.y) * ihx;
    cx0[3] = 2.0f * (a00.x - a01.x) * ihx3 + (a00.y + a01.y) * ihx2;
    cy0[0] = b00.x; cy0[1] = b00.y;
    cy0[2] = 3.0f * (b01.x - b00.x) * ihy2 - (2.0f * b00.y + b01.y) * ihy;
    cy0[3] = 2.0f * (b00.x - b01.x) * ihy3 + (b00.y + b01.y) * ihy2;
    cx1[0] = a10.x; cx1[1] = a10.y;
    cx1[2] = 3.0f * (a11.x - a10.x) * ihx2 - (2.0f * a10.y + a11.y) * ihx;
    cx1[3] = 2.0f * (a10.x - a11.x) * ihx3 + (a10.y + a11.y) * ihx2;
    cy1[0] = b10.x; cy1[1] = b10.y;
    cy1[2] = 3.0f * (b11.x - b10.x) * ihy2 - (2.0f * b10.y + b11.y) * ihy;
    cy1[3] = 2.0f * (b10.x - b11.x) * ihy3 + (b10.y + b11.y) * ihy2;

    // Pair products, order (0,0),(0,1),(0,2),(0,3),(1,1),(1,2),(1,3),(2,2),(2,3),(3,3)
    float X0[10], Y0[10], X1[10], Y1[10];
    {
        int q = 0;
        #pragma unroll
        for (int a = 0; a < 4; ++a)
            #pragma unroll
            for (int a2 = a; a2 < 4; ++a2) {
                X0[q] = cx0[a] * cx0[a2];
                X1[q] = cx1[a] * cx1[a2];
                Y0[q] = cy0[a] * cy0[a2];
                Y1[q] = cy1[a] * cy1[a2];
                ++q;
            }
    }

    // Z = X^T D Y — D is wave-uniform, each element used for both bm slots.
    const float* __restrict__ Dp = ws + blk * D_STRIDE;
    float s0 = 0.0f, s1 = 0.0f;
    #pragma unroll
    for (int al = 0; al < 10; ++al) {
        float w0 = 0.0f, w1 = 0.0f;
        #pragma unroll
        for (int be = 0; be < 10; ++be) {
            const float d = Dp[al * 10 + be];
            w0 = fmaf(d, Y0[be], w0);
            w1 = fmaf(d, Y1[be], w1);
        }
        s0 = fmaf(X0[al], w0, s0);
        s1 = fmaf(X1[al], w1, s1);
    }

    float* __restrict__ zout = out + POLY_FLOATS;
    zout[bm0 * Z_STRIDE + blk] = s0;
    zout[bm1 * Z_STRIDE + blk] = s1;
}

extern "C" void kernel_launch(void* const* d_in, const int* in_sizes, int n_in,
                              void* d_out, int out_size, void* d_ws, size_t ws_size,
                              hipStream_t stream) {
    const float* params = (const float*)d_in[0];
    const float* knots  = (const float*)d_in[1];
    const float* coeffs = (const float*)d_in[2];
    float* out = (float*)d_out;
    float* ws  = (float*)d_ws;
    (void)in_sizes; (void)n_in; (void)out_size; (void)ws_size;

    spline_prepass<<<KC * KC, 128, 0, stream>>>(coeffs, ws);
    spline_main<<<KC * KC, 256, 0, stream>>>(params, knots, ws, out);
}